// Round 9
// baseline (359.476 us; speedup 1.0000x reference)
//
#include <hip/hip_runtime.h>
#include <hip/hip_fp16.h>
#include <hip/hip_bf16.h>

#define NN 50000
#define EE 800000
#define NSLICE 8
#define SLICE 6250            // 50000/8; x slice = 6250*128B = 0.8MB << 4MB XCD L2
#define EBLK 3125             // EE / 256 exactly (build kernels: 3125 blocks x 256 thr)

// ---- workspace layout (proven-safe 12.8MB + flag envelope) ----
// records (uint2 sd,eid per edge = 6.4MB) live in d_out, which mlp overwrites last.
// R7 CRASH FIX: cur8 at 6400032 so ONE 64-byte memset covers cnt8+cur8.
#define OFF_AGGH 0ull            // 50000*64*2 = 6,400,000
#define OFF_CNT  6400000ull      // 8*4 = 32   bin counts   [6400000, 6400032)
#define OFF_CUR  6400032ull      // 8*4 = 32   bin cursors  [6400032, 6400064)
#define OFF_FLAG 12800000ull     // proven-safe flag offset

__device__ __forceinline__ float bflo(unsigned u) { return __uint_as_float(u << 16); }
__device__ __forceinline__ float bfhi(unsigned u) { return __uint_as_float(u & 0xffff0000u); }

__device__ __forceinline__ void load_edge(const int* __restrict__ ei, bool idx64, int e,
                                          int& src, int& dst) {
    const long long* __restrict__ ei64 = (const long long*)ei;
    if (idx64) { src = (int)ei64[e]; dst = (int)ei64[EE + e]; }
    else       { src = ei[e];        dst = ei[EE + e]; }
}

// hist of 8 src-slices (LDS-staged) + dtype detect (block 0). flag=1 if bf16.
__global__ __launch_bounds__(256) void hist_detect_kernel(const int* __restrict__ ei,
                                                          const unsigned* __restrict__ xw,
                                                          int* __restrict__ cnt8,
                                                          int* __restrict__ flag) {
    __shared__ int h[8];
    const int tid = threadIdx.x;
    if (tid < 8) h[tid] = 0;
    __syncthreads();
    const int oddor = ei[1] | ei[3] | ei[5] | ei[7] | ei[9] | ei[11] | ei[13] | ei[15];
    const bool idx64 = (oddor == 0);
    int src, dst;
    load_edge(ei, idx64, blockIdx.x * 256 + tid, src, dst);
    atomicAdd(&h[src / SLICE], 1);
    __syncthreads();
    if (tid < 8) atomicAdd(&cnt8[tid], h[tid]);
    if (blockIdx.x == 0 && tid < 64) {
        unsigned ex = (xw[tid] >> 7) & 0xFFu;
        unsigned long long m = __ballot(ex >= 100u && ex <= 140u);
        if (tid == 0) *flag = (__popcll(m) >= 32) ? 1 : 0;
    }
}

// 8-bin counting-sort scatter: recs[slice regions] = uint2{ src|dst<<16, eid }
__global__ __launch_bounds__(256) void bin_kernel(const int* __restrict__ ei,
                                                  const int* __restrict__ cnt8,
                                                  int* __restrict__ cur8,
                                                  uint2* __restrict__ recs) {
    __shared__ int lcnt[8], gb[8], pre[8];
    const int tid = threadIdx.x;
    if (tid < 8) lcnt[tid] = 0;
    __syncthreads();
    const int oddor = ei[1] | ei[3] | ei[5] | ei[7] | ei[9] | ei[11] | ei[13] | ei[15];
    const bool idx64 = (oddor == 0);
    const int e = blockIdx.x * 256 + tid;
    int src, dst;
    load_edge(ei, idx64, e, src, dst);
    const int p = src / SLICE;
    const int lrank = atomicAdd(&lcnt[p], 1);
    __syncthreads();
    if (tid < 8) {
        gb[tid] = atomicAdd(&cur8[tid], lcnt[tid]);
        int s = 0;
        for (int i = 0; i < tid; i++) s += cnt8[i];
        pre[tid] = s;
    }
    __syncthreads();
    recs[pre[p] + gb[p] + lrank] =
        make_uint2((unsigned)src | ((unsigned)dst << 16), (unsigned)e);
}

// edge_attr row (wave-broadcast) dot We column — plain cached loads (R3: never nt)
template <bool BF16>
__device__ __forceinline__ float edge_lin(const void* __restrict__ eav, int e,
                                          const float* __restrict__ we, float bed) {
    float acc = bed;
    if constexpr (BF16) {
        const uint4* row = (const uint4*)((const __hip_bfloat16*)eav + (size_t)e * 16);
        const uint4 p0 = row[0];
        const uint4 p1 = row[1];
        acc = fmaf(bflo(p0.x), we[0],  acc); acc = fmaf(bfhi(p0.x), we[1],  acc);
        acc = fmaf(bflo(p0.y), we[2],  acc); acc = fmaf(bfhi(p0.y), we[3],  acc);
        acc = fmaf(bflo(p0.z), we[4],  acc); acc = fmaf(bfhi(p0.z), we[5],  acc);
        acc = fmaf(bflo(p0.w), we[6],  acc); acc = fmaf(bfhi(p0.w), we[7],  acc);
        acc = fmaf(bflo(p1.x), we[8],  acc); acc = fmaf(bfhi(p1.x), we[9],  acc);
        acc = fmaf(bflo(p1.y), we[10], acc); acc = fmaf(bfhi(p1.y), we[11], acc);
        acc = fmaf(bflo(p1.z), we[12], acc); acc = fmaf(bfhi(p1.z), we[13], acc);
        acc = fmaf(bflo(p1.w), we[14], acc); acc = fmaf(bfhi(p1.w), we[15], acc);
    } else {
        const float4* row = (const float4*)((const float*)eav + (size_t)e * 16);
        const float4 q0 = row[0], q1 = row[1], q2 = row[2], q3 = row[3];
        acc = fmaf(q0.x, we[0],  acc); acc = fmaf(q0.y, we[1],  acc);
        acc = fmaf(q0.z, we[2],  acc); acc = fmaf(q0.w, we[3],  acc);
        acc = fmaf(q1.x, we[4],  acc); acc = fmaf(q1.y, we[5],  acc);
        acc = fmaf(q1.z, we[6],  acc); acc = fmaf(q1.w, we[7],  acc);
        acc = fmaf(q2.x, we[8],  acc); acc = fmaf(q2.y, we[9],  acc);
        acc = fmaf(q2.z, we[10], acc); acc = fmaf(q2.w, we[11], acc);
        acc = fmaf(q3.x, we[12], acc); acc = fmaf(q3.y, we[13], acc);
        acc = fmaf(q3.z, we[14], acc); acc = fmaf(q3.w, we[15], acc);
    }
    return acc;
}

template <bool BF16>
__device__ __forceinline__ float loadx(const void* __restrict__ xv, int s, int d) {
    if constexpr (BF16)
        return __bfloat162float(((const __hip_bfloat16*)xv)[(size_t)s * 64 + d]);
    else
        return ((const float*)xv)[(size_t)s * 64 + d];
}

// ---- XCD-sliced edge aggregation over pre-binned records ----
// block g: slice p = g%8 (XCD-confined x reads), chunk c = g/8 of slice p's region.
template <bool BF16>
__device__ __forceinline__ void slice_body(
    const void* __restrict__ xv, const uint2* __restrict__ recs,
    const int* __restrict__ cnt8,
    const void* __restrict__ eav, const void* __restrict__ Wev,
    const void* __restrict__ bev, __half2* __restrict__ aggh)
{
    const int tid = threadIdx.x;
    const int d   = tid & 63;
    const int sub = tid >> 6;
    const int p   = blockIdx.x & 7;
    const int c   = blockIdx.x >> 3;

    float we[16];
    float bed;
    if constexpr (BF16) {
        const __hip_bfloat16* We = (const __hip_bfloat16*)Wev;
#pragma unroll
        for (int k = 0; k < 16; k++) we[k] = __bfloat162float(We[k * 64 + d]);
        bed = __bfloat162float(((const __hip_bfloat16*)bev)[d]);
    } else {
        const float* We = (const float*)Wev;
#pragma unroll
        for (int k = 0; k < 16; k++) we[k] = We[k * 64 + d];
        bed = ((const float*)bev)[d];
    }

    // region of slice p
    int B = 0;
#pragma unroll
    for (int i = 0; i < 8; i++) B += (i < p) ? cnt8[i] : 0;
    const int C = cnt8[p];
    // this block's chunk, then this wave's quarter
    const int lo = B + (int)((long long)C * c / 256);
    const int hi = B + (int)((long long)C * (c + 1) / 256);
    const int w0 = lo + (int)((long long)(hi - lo) * sub / 4);
    const int w1 = lo + (int)((long long)(hi - lo) * (sub + 1) / 4);

    int k = w0;
    for (; k + 4 <= w1; k += 4) {
        const uint2 r0 = recs[k],     r1 = recs[k + 1];
        const uint2 r2 = recs[k + 2], r3 = recs[k + 3];
        const int s0 = r0.x & 0xFFFFu, t0 = r0.x >> 16, e0 = (int)r0.y;
        const int s1 = r1.x & 0xFFFFu, t1 = r1.x >> 16, e1 = (int)r1.y;
        const int s2 = r2.x & 0xFFFFu, t2 = r2.x >> 16, e2 = (int)r2.y;
        const int s3 = r3.x & 0xFFFFu, t3 = r3.x >> 16, e3 = (int)r3.y;
        const float x0 = loadx<BF16>(xv, s0, d);
        const float x1 = loadx<BF16>(xv, s1, d);
        const float x2 = loadx<BF16>(xv, s2, d);
        const float x3 = loadx<BF16>(xv, s3, d);
        const float a0f = edge_lin<BF16>(eav, e0, we, bed);
        const float a1f = edge_lin<BF16>(eav, e1, we, bed);
        const float a2f = edge_lin<BF16>(eav, e2, we, bed);
        const float a3f = edge_lin<BF16>(eav, e3, we, bed);
        const float m0 = fmaxf(a0f + x0, 0.0f);
        const float m1 = fmaxf(a1f + x1, 0.0f);
        const float m2 = fmaxf(a2f + x2, 0.0f);
        const float m3 = fmaxf(a3f + x3, 0.0f);
        const float o0 = __shfl_xor(m0, 1);
        const float o1 = __shfl_xor(m1, 1);
        const float o2 = __shfl_xor(m2, 1);
        const float o3 = __shfl_xor(m3, 1);
        if ((d & 1) == 0) {
            const int h = d >> 1;
            unsafeAtomicAdd(aggh + (size_t)t0 * 32 + h, __floats2half2_rn(m0, o0));
            unsafeAtomicAdd(aggh + (size_t)t1 * 32 + h, __floats2half2_rn(m1, o1));
            unsafeAtomicAdd(aggh + (size_t)t2 * 32 + h, __floats2half2_rn(m2, o2));
            unsafeAtomicAdd(aggh + (size_t)t3 * 32 + h, __floats2half2_rn(m3, o3));
        }
    }
    for (; k < w1; ++k) {
        const uint2 r = recs[k];
        const int s0 = r.x & 0xFFFFu, t0 = r.x >> 16, e0 = (int)r.y;
        const float xs  = loadx<BF16>(xv, s0, d);
        const float a   = edge_lin<BF16>(eav, e0, we, bed);
        const float msg = fmaxf(a + xs, 0.0f);
        const float oth = __shfl_xor(msg, 1);
        if ((d & 1) == 0)
            unsafeAtomicAdd(aggh + (size_t)t0 * 32 + (d >> 1), __floats2half2_rn(msg, oth));
    }
}

__global__ __launch_bounds__(256) void slice_agg_kernel(
    const void* x, const uint2* recs, const int* cnt8, const void* ea,
    const void* We, const void* be, __half2* aggh, const int* flag)
{
    if (*flag) slice_body<true >(x, recs, cnt8, ea, We, be, aggh);
    else       slice_body<false>(x, recs, cnt8, ea, We, be, aggh);
}

// ---------------- MLP: 4-accumulator ILP (serial fmaf chain 64 -> 16) ----------------
template <bool BF16>
__device__ __forceinline__ void mlp_body(
    const void* __restrict__ xv, const __half* __restrict__ aggh,
    const void* __restrict__ W1v, const void* __restrict__ b1v,
    const void* __restrict__ W2v, const void* __restrict__ b2v,
    void* __restrict__ outv, float (*sh)[64], float (*st)[64])
{
    const int tid = threadIdx.x;
    const int d   = tid & 63;
    const int w   = tid >> 6;

    float w1c[64], w2c[64], b1d, b2d;
    if constexpr (BF16) {
        const __hip_bfloat16* W1 = (const __hip_bfloat16*)W1v;
        const __hip_bfloat16* W2 = (const __hip_bfloat16*)W2v;
#pragma unroll
        for (int k = 0; k < 64; k++) {
            w1c[k] = __bfloat162float(W1[k * 64 + d]);
            w2c[k] = __bfloat162float(W2[k * 64 + d]);
        }
        b1d = __bfloat162float(((const __hip_bfloat16*)b1v)[d]);
        b2d = __bfloat162float(((const __hip_bfloat16*)b2v)[d]);
    } else {
        const float* W1 = (const float*)W1v;
        const float* W2 = (const float*)W2v;
#pragma unroll
        for (int k = 0; k < 64; k++) {
            w1c[k] = W1[k * 64 + d];
            w2c[k] = W2[k * 64 + d];
        }
        b1d = ((const float*)b1v)[d];
        b2d = ((const float*)b2v)[d];
    }

    const int stride = gridDim.x * 4;
    int node = blockIdx.x * 4 + w;

    float xs_n = 0.0f, ag_n = 0.0f;
    if (node < NN) {
        if constexpr (BF16) xs_n = __bfloat162float(((const __hip_bfloat16*)xv)[(size_t)node * 64 + d]);
        else                xs_n = ((const float*)xv)[(size_t)node * 64 + d];
        ag_n = __half2float(aggh[(size_t)node * 64 + d]);
    }

    while (node < NN) {
        const float xs_c = xs_n, ag_c = ag_n;
        const int next = node + stride;
        if (next < NN) {
            if constexpr (BF16) xs_n = __bfloat162float(((const __hip_bfloat16*)xv)[(size_t)next * 64 + d]);
            else                xs_n = ((const float*)xv)[(size_t)next * 64 + d];
            ag_n = __half2float(aggh[(size_t)next * 64 + d]);
        }

        sh[w][d] = xs_c + ag_c;

        float t0 = 0.0f, t1 = 0.0f, t2 = 0.0f, t3 = 0.0f;
        const float4* hv = (const float4*)sh[w];
#pragma unroll
        for (int k = 0; k < 16; k++) {
            const float4 hq = hv[k];
            t0 = fmaf(hq.x, w1c[4 * k],     t0);
            t1 = fmaf(hq.y, w1c[4 * k + 1], t1);
            t2 = fmaf(hq.z, w1c[4 * k + 2], t2);
            t3 = fmaf(hq.w, w1c[4 * k + 3], t3);
        }
        const float t = fmaxf(b1d + ((t0 + t1) + (t2 + t3)), 0.0f);
        st[w][d] = t;

        float o0 = 0.0f, o1 = 0.0f, o2 = 0.0f, o3 = 0.0f;
        const float4* tv = (const float4*)st[w];
#pragma unroll
        for (int k = 0; k < 16; k++) {
            const float4 tq = tv[k];
            o0 = fmaf(tq.x, w2c[4 * k],     o0);
            o1 = fmaf(tq.y, w2c[4 * k + 1], o1);
            o2 = fmaf(tq.z, w2c[4 * k + 2], o2);
            o3 = fmaf(tq.w, w2c[4 * k + 3], o3);
        }
        const float o = b2d + ((o0 + o1) + (o2 + o3));
        if constexpr (BF16) ((__hip_bfloat16*)outv)[(size_t)node * 64 + d] = __float2bfloat16(o);
        else                ((float*)outv)[(size_t)node * 64 + d] = o;
        node = next;
    }
}

__global__ __launch_bounds__(256) void mlp_kernel(
    const void* x, const __half* aggh,
    const void* W1, const void* b1, const void* W2, const void* b2,
    void* out, const int* flag)
{
    __shared__ float sh[4][64];
    __shared__ float st[4][64];
    if (*flag) mlp_body<true >(x, aggh, W1, b1, W2, b2, out, sh, st);
    else       mlp_body<false>(x, aggh, W1, b1, W2, b2, out, sh, st);
}

extern "C" void kernel_launch(void* const* d_in, const int* in_sizes, int n_in,
                              void* d_out, int out_size, void* d_ws, size_t ws_size,
                              hipStream_t stream) {
    const void* x          = d_in[0];
    const int*  edge_index = (const int*)d_in[1];
    const void* edge_attr  = d_in[2];
    const void* We         = d_in[3];
    const void* be         = d_in[4];
    const void* W1         = d_in[5];
    const void* b1         = d_in[6];
    const void* W2         = d_in[7];
    const void* b2         = d_in[8];

    char* ws = (char*)d_ws;
    __half* aggh = (__half*)(ws + OFF_AGGH);
    int*    cnt8 = (int*)(ws + OFF_CNT);
    int*    cur8 = (int*)(ws + OFF_CUR);
    int*    flag = (int*)(ws + OFF_FLAG);
    uint2*  recs = (uint2*)d_out;          // 800000*8B = 6.4MB scratch; mlp overwrites last

    hipMemsetAsync(aggh, 0, (size_t)NN * 64 * sizeof(__half), stream);
    hipMemsetAsync(cnt8, 0, 64, stream);   // covers cnt8 [+0,32) AND cur8 [+32,64)
    hipLaunchKernelGGL(hist_detect_kernel, dim3(EBLK), dim3(256), 0, stream,
                       edge_index, (const unsigned*)x, cnt8, flag);
    hipLaunchKernelGGL(bin_kernel, dim3(EBLK), dim3(256), 0, stream,
                       edge_index, cnt8, cur8, recs);
    hipLaunchKernelGGL(slice_agg_kernel, dim3(NSLICE * 256), dim3(256), 0, stream,
                       x, recs, cnt8, edge_attr, We, be, (__half2*)aggh, flag);
    hipLaunchKernelGGL(mlp_kernel, dim3(768), dim3(256), 0, stream,
                       x, aggh, W1, b1, W2, b2, d_out, flag);
}